// Round 2
// baseline (676.620 us; speedup 1.0000x reference)
//
#include <hip/hip_runtime.h>
#include <hip/hip_bf16.h>

// L21 norm: out = sum_c sqrt(sum_r S[r,c]^2), S is fp32 [8192, 16384] row-major.
// Memory-bound streaming reduction: 512 MiB read, floor ~80 us at 6.4 TB/s
// (the harness's own 2 GiB ws-poison fill runs at 6.4 TB/s — that's the ceiling).
//
// Structure: kernel1 computes per-(row-chunk, column) partial sums of squares
// (coalesced float4 columns, nt loads), kernel2 folds CHUNKS partials per
// column, sqrts, and block+atomic reduces to the scalar.

#define N_ROWS 8192
#define N_COLS 16384
#define CHUNKS 64                      // 64 row chunks -> grid (16,64) = 1024 blocks
#define ROWS_PER_CHUNK (N_ROWS / CHUNKS)   // 128
#define THREADS 256
#define COLS_PER_BLOCK (THREADS * 4)   // float4 per thread -> 1024 cols/block

typedef float f32x4 __attribute__((ext_vector_type(4)));

__device__ __forceinline__ f32x4 nt_load(const f32x4* p) {
    return __builtin_nontemporal_load(p);
}

// Kernel 1: partial[chunk][col] = sum over 128 rows of S[r,col]^2
__global__ __launch_bounds__(THREADS) void l21_partial_kernel(
    const float* __restrict__ S, float* __restrict__ partial) {
    const int col4 = blockIdx.x * COLS_PER_BLOCK + threadIdx.x * 4;
    const int r0   = blockIdx.y * ROWS_PER_CHUNK;

    const f32x4* p = (const f32x4*)(S + (size_t)r0 * N_COLS + col4);
    f32x4 acc = (f32x4)(0.f);
#pragma unroll 16
    for (int r = 0; r < ROWS_PER_CHUNK; ++r) {
        f32x4 v = nt_load(p + (size_t)r * (N_COLS / 4));
        acc += v * v;
    }
    *(f32x4*)(partial + (size_t)blockIdx.y * N_COLS + col4) = acc;
}

// Kernel 2: per column fold CHUNKS partials, sqrt, reduce to scalar.
// 64 blocks x 256 threads: one thread per column; 4 MiB total read.
__global__ __launch_bounds__(THREADS) void l21_finish_kernel(
    const float* __restrict__ partial, float* __restrict__ out) {
    const int col = blockIdx.x * THREADS + threadIdx.x;

    float s = 0.f;
#pragma unroll
    for (int c = 0; c < CHUNKS; ++c)
        s += partial[(size_t)c * N_COLS + col];  // coalesced across threads
    float v = sqrtf(s);

    // wave-64 shuffle reduction
#pragma unroll
    for (int off = 32; off > 0; off >>= 1)
        v += __shfl_down(v, off, 64);

    __shared__ float wsum[THREADS / 64];
    const int lane = threadIdx.x & 63;
    const int wave = threadIdx.x >> 6;
    if (lane == 0) wsum[wave] = v;
    __syncthreads();

    if (threadIdx.x == 0) {
        float t = 0.f;
#pragma unroll
        for (int w = 0; w < THREADS / 64; ++w) t += wsum[w];
        atomicAdd(out, t);  // 64 blocks, device-scope default
    }
}

extern "C" void kernel_launch(void* const* d_in, const int* in_sizes, int n_in,
                              void* d_out, int out_size, void* d_ws, size_t ws_size,
                              hipStream_t stream) {
    const float* S = (const float*)d_in[0];
    float* out     = (float*)d_out;
    float* partial = (float*)d_ws;  // CHUNKS * N_COLS * 4 = 4 MiB of the 2 GiB ws

    // d_out is poisoned 0xAA before every timed launch -> zero it (capture-safe).
    hipMemsetAsync(out, 0, sizeof(float), stream);

    dim3 grid1(N_COLS / COLS_PER_BLOCK, CHUNKS);  // (16, 64) = 1024 blocks
    l21_partial_kernel<<<grid1, THREADS, 0, stream>>>(S, partial);

    dim3 grid2(N_COLS / THREADS);  // 64 blocks
    l21_finish_kernel<<<grid2, THREADS, 0, stream>>>(partial, out);
}